// Round 1
// baseline (8346.365 us; speedup 1.0000x reference)
//
#include <hip/hip_runtime.h>
#include <hip/hip_bf16.h>
#include <stdint.h>

// Problem constants
#define T_SEQ 256
#define BATCH 32
#define EDIM  512
#define G4    2048      // 4*E
#define VOCAB 16000
#define ROWS  8192      // B*T

typedef unsigned short u16;
typedef short bf16x8 __attribute__((ext_vector_type(8)));   // 8 bf16 = 4 VGPRs (MFMA A/B frag)
typedef float f32x4  __attribute__((ext_vector_type(4)));   // MFMA C/D frag

__device__ __forceinline__ u16 f2bf(float x) {              // RNE f32 -> bf16
  union { float f; uint32_t u; } v; v.f = x;
  return (u16)((v.u + 0x7fffu + ((v.u >> 16) & 1u)) >> 16);
}
__device__ __forceinline__ float bf2f(u16 x) {
  union { uint32_t u; float f; } v; v.u = ((uint32_t)x) << 16;
  return v.f;
}
__device__ __forceinline__ float sig_(float x) { return 1.0f / (1.0f + __expf(-x)); }
__device__ __forceinline__ float tanh_(float x) { return 2.0f / (1.0f + __expf(-2.0f * x)) - 1.0f; }

// ---------------------------------------------------------------- zero init
__global__ void zero_kernel(uint4* __restrict__ p, int n16) {
  int i = blockIdx.x * 256 + threadIdx.x;
  if (i < n16) p[i] = make_uint4(0u, 0u, 0u, 0u);
}

// ---------------------------------------------------------------- embedding gather (f32 -> bf16)
__global__ void gather_kernel(const int* __restrict__ inputs, const float* __restrict__ Emat,
                              u16* __restrict__ out) {
  const int r = blockIdx.x;                 // r = b*T + t (natural [B,T] flat order)
  const int idx = inputs[r];
  const float* src = Emat + (size_t)idx * EDIM;
  u16* dst = out + (size_t)r * EDIM;
  for (int e = threadIdx.x; e < EDIM; e += 256) dst[e] = f2bf(src[e]);
}

// ---------------------------------------------------------------- transpose + cast: src[K][N] f32 -> dst rows n: dst[n*stride + off + k] bf16
__global__ void transpose_cast_kernel(const float* __restrict__ src, u16* __restrict__ dst,
                                      int srcCols, int dstStride, int dstColOff) {
  __shared__ float tile[32][33];
  const int n0 = blockIdx.x * 32, k0 = blockIdx.y * 32;
  const int tx = threadIdx.x & 31, ty = threadIdx.x >> 5;   // 32 x 8
  #pragma unroll
  for (int p = 0; p < 32; p += 8)
    tile[ty + p][tx] = src[(size_t)(k0 + ty + p) * srcCols + n0 + tx];
  __syncthreads();
  #pragma unroll
  for (int p = 0; p < 32; p += 8)
    dst[(size_t)(n0 + ty + p) * dstStride + dstColOff + k0 + tx] = f2bf(tile[tx][ty + p]);
}

// ---------------------------------------------------------------- bf16 MFMA GEMM: C[M][N] = A[M][K] * BT[N][K]^T (+bias)
// 128x128 tile, 4 waves in 2x2 (64x64 each = 4x4 MFMA tiles), BK=32.
// LDS rows padded to 40 bf16 (80B = 16B-aligned, 2-way max bank aliasing = free).
template<int OUT_BF16, int HAS_BIAS>
__launch_bounds__(256)
__global__ void gemm_bt_kernel(const u16* __restrict__ A, const u16* __restrict__ BT,
                               void* __restrict__ Cv, const float* __restrict__ bias,
                               int M, int N, int K) {
  __shared__ u16 sA[128 * 40];
  __shared__ u16 sB[128 * 40];
  const int tid = threadIdx.x;
  const int lane = tid & 63, wave = tid >> 6;
  const int wm = wave & 1, wn = wave >> 1;
  const int mr = lane & 15, kq = lane >> 4;
  const int row0 = blockIdx.y * 128, col0 = blockIdx.x * 128;
  const int srow = tid >> 2, scol = (tid & 3) * 8;          // 4 thr/row * 16B, 64 rows/pass
  f32x4 acc[4][4];
  #pragma unroll
  for (int i = 0; i < 4; ++i)
    #pragma unroll
    for (int j = 0; j < 4; ++j) acc[i][j] = (f32x4){0.f, 0.f, 0.f, 0.f};

  for (int k0 = 0; k0 < K; k0 += 32) {
    *(uint4*)&sA[srow * 40 + scol]        = *(const uint4*)&A[(size_t)(row0 + srow) * K + k0 + scol];
    *(uint4*)&sA[(srow + 64) * 40 + scol] = *(const uint4*)&A[(size_t)(row0 + srow + 64) * K + k0 + scol];
    *(uint4*)&sB[srow * 40 + scol]        = *(const uint4*)&BT[(size_t)(col0 + srow) * K + k0 + scol];
    *(uint4*)&sB[(srow + 64) * 40 + scol] = *(const uint4*)&BT[(size_t)(col0 + srow + 64) * K + k0 + scol];
    __syncthreads();
    bf16x8 af[4], bfr[4];
    #pragma unroll
    for (int i = 0; i < 4; ++i) af[i] = *(const bf16x8*)&sA[(wm * 64 + i * 16 + mr) * 40 + kq * 8];
    #pragma unroll
    for (int j = 0; j < 4; ++j) bfr[j] = *(const bf16x8*)&sB[(wn * 64 + j * 16 + mr) * 40 + kq * 8];
    #pragma unroll
    for (int i = 0; i < 4; ++i)
      #pragma unroll
      for (int j = 0; j < 4; ++j)
        acc[i][j] = __builtin_amdgcn_mfma_f32_16x16x32_bf16(af[i], bfr[j], acc[i][j], 0, 0, 0);
    __syncthreads();
  }
  // epilogue: C/D layout col=lane&15, row=(lane>>4)*4+reg  [verified m89/m91]
  #pragma unroll
  for (int j = 0; j < 4; ++j) {
    const int col = col0 + wn * 64 + j * 16 + mr;
    const float bv = HAS_BIAS ? bias[col] : 0.0f;
    #pragma unroll
    for (int i = 0; i < 4; ++i) {
      const int rbase = row0 + wm * 64 + i * 16 + kq * 4;
      #pragma unroll
      for (int r = 0; r < 4; ++r) {
        const float v = acc[i][j][r] + bv;
        if (OUT_BF16) ((u16*)Cv)[(size_t)(rbase + r) * N + col] = f2bf(v);
        else          ((float*)Cv)[(size_t)(rbase + r) * N + col] = v;
      }
    }
  }
}

// ---------------------------------------------------------------- persistent LSTM
// 64 blocks x 256 thr; block owns e-slice [e0, e0+8) -> 32 gate cols (region-major i,j,f,o).
// Grid barrier: device-scope atomic + __threadfence (cross-XCD L2 coherence, Guideline 16).
__device__ __forceinline__ void grid_barrier(unsigned* ctr, unsigned nbar) {
  __syncthreads();
  if (threadIdx.x == 0) {
    __threadfence();
    __hip_atomic_fetch_add(ctr, 1u, __ATOMIC_RELEASE, __HIP_MEMORY_SCOPE_AGENT);
    const unsigned target = nbar * (unsigned)gridDim.x;
    while (__hip_atomic_load(ctr, __ATOMIC_ACQUIRE, __HIP_MEMORY_SCOPE_AGENT) < target) {}
  }
  __syncthreads();
  __threadfence();   // all threads: invalidate L1/L2-stale before consuming peers' h
}

#define CK   256        // K staging chunk (keeps LDS at ~38 KB)
#define LROW 264        // CK + 8 pad bf16: 528B row = 16B aligned; dword stride 132 -> 2-way banks

__launch_bounds__(256)
__global__ void lstm_kernel(const u16* __restrict__ Xpre0, const u16* __restrict__ Wh0T,
                            const u16* __restrict__ W1T,
                            const float* __restrict__ b0, const float* __restrict__ b1,
                            u16* __restrict__ Hbuf0, u16* __restrict__ H1buf,
                            float* __restrict__ C0, float* __restrict__ C1,
                            u16* __restrict__ H1all, unsigned* __restrict__ ctr) {
  __shared__ u16 sA[32 * LROW];
  __shared__ u16 sB[32 * LROW];
  __shared__ float sG[32 * 33];
  const int tid = threadIdx.x;
  const int lane = tid & 63, wave = tid >> 6;
  const int wm = wave & 1, wn = wave >> 1;        // 2x2 waves over [32b x 32gc] (4 16x16 tiles)
  const int mr = lane & 15, kq = lane >> 4;
  const int e0 = blockIdx.x * 8;
  const int ub = tid >> 3, ue = tid & 7;          // update mapping: (batch, e-idx), 32x8=256
  float bias0[4], bias1[4];
  #pragma unroll
  for (int g = 0; g < 4; ++g) {
    bias0[g] = b0[g * EDIM + e0 + ue];
    bias1[g] = b1[g * EDIM + e0 + ue];
  }
  unsigned nbar = 0;

  for (int t = 0; t < T_SEQ; ++t) {
    const int rs = t & 1, wsl = rs ^ 1;           // read/write ping-pong slots
    // ======== layer 0: G = h0(t-1) @ Wh0  (x-part precomputed in Xpre0) ========
    {
      const u16* hsrc = Hbuf0 + rs * BATCH * EDIM;
      f32x4 acc = (f32x4){0.f, 0.f, 0.f, 0.f};
      for (int c0 = 0; c0 < EDIM; c0 += CK) {
        for (int idx = tid; idx < 32 * (CK / 8); idx += 256) {
          int r = idx >> 5, c = idx & 31;
          *(uint4*)&sA[r * LROW + c * 8] = *(const uint4*)&hsrc[r * EDIM + c0 + c * 8];
        }
        for (int idx = tid; idx < 32 * (CK / 8); idx += 256) {
          int r = idx >> 5, c = idx & 31;
          int gc = (r >> 3) * EDIM + e0 + (r & 7);
          *(uint4*)&sB[r * LROW + c * 8] = *(const uint4*)&Wh0T[(size_t)gc * EDIM + c0 + c * 8];
        }
        __syncthreads();
        #pragma unroll
        for (int ks = 0; ks < CK / 32; ++ks) {
          bf16x8 a = *(const bf16x8*)&sA[(wm * 16 + mr) * LROW + ks * 32 + kq * 8];
          bf16x8 b = *(const bf16x8*)&sB[(wn * 16 + mr) * LROW + ks * 32 + kq * 8];
          acc = __builtin_amdgcn_mfma_f32_16x16x32_bf16(a, b, acc, 0, 0, 0);
        }
        __syncthreads();
      }
      #pragma unroll
      for (int r = 0; r < 4; ++r)
        sG[(wm * 16 + kq * 4 + r) * 33 + wn * 16 + mr] = acc[r];
      __syncthreads();
      // gate math (fp32), c stays fp32; h published as bf16
      const size_t xbase = ((size_t)ub * T_SEQ + t) * G4;
      const float cold = C0[ub * EDIM + e0 + ue];
      const float gi = sG[ub * 33 + 0 * 8 + ue] + bias0[0] + bf2f(Xpre0[xbase + 0 * EDIM + e0 + ue]);
      const float gj = sG[ub * 33 + 1 * 8 + ue] + bias0[1] + bf2f(Xpre0[xbase + 1 * EDIM + e0 + ue]);
      const float gf = sG[ub * 33 + 2 * 8 + ue] + bias0[2] + bf2f(Xpre0[xbase + 2 * EDIM + e0 + ue]);
      const float go = sG[ub * 33 + 3 * 8 + ue] + bias0[3] + bf2f(Xpre0[xbase + 3 * EDIM + e0 + ue]);
      const float cn = sig_(gf + 1.0f) * cold + sig_(gi) * tanh_(gj);
      const float hn = sig_(go) * tanh_(cn);
      C0[ub * EDIM + e0 + ue] = cn;
      Hbuf0[wsl * BATCH * EDIM + ub * EDIM + e0 + ue] = f2bf(hn);
    }
    grid_barrier(ctr, ++nbar);
    // ======== layer 1: G = [h0(t) | h1(t-1)] @ [Wx1; Wh1] ========
    {
      f32x4 acc = (f32x4){0.f, 0.f, 0.f, 0.f};
      for (int c0 = 0; c0 < 2 * EDIM; c0 += CK) {
        const u16* hsrc = (c0 < EDIM) ? (Hbuf0 + wsl * BATCH * EDIM + c0)
                                      : (H1buf + rs * BATCH * EDIM + (c0 - EDIM));
        for (int idx = tid; idx < 32 * (CK / 8); idx += 256) {
          int r = idx >> 5, c = idx & 31;
          *(uint4*)&sA[r * LROW + c * 8] = *(const uint4*)&hsrc[r * EDIM + c * 8];
        }
        for (int idx = tid; idx < 32 * (CK / 8); idx += 256) {
          int r = idx >> 5, c = idx & 31;
          int gc = (r >> 3) * EDIM + e0 + (r & 7);
          *(uint4*)&sB[r * LROW + c * 8] = *(const uint4*)&W1T[(size_t)gc * (2 * EDIM) + c0 + c * 8];
        }
        __syncthreads();
        #pragma unroll
        for (int ks = 0; ks < CK / 32; ++ks) {
          bf16x8 a = *(const bf16x8*)&sA[(wm * 16 + mr) * LROW + ks * 32 + kq * 8];
          bf16x8 b = *(const bf16x8*)&sB[(wn * 16 + mr) * LROW + ks * 32 + kq * 8];
          acc = __builtin_amdgcn_mfma_f32_16x16x32_bf16(a, b, acc, 0, 0, 0);
        }
        __syncthreads();
      }
      #pragma unroll
      for (int r = 0; r < 4; ++r)
        sG[(wm * 16 + kq * 4 + r) * 33 + wn * 16 + mr] = acc[r];
      __syncthreads();
      const float cold = C1[ub * EDIM + e0 + ue];
      const float gi = sG[ub * 33 + 0 * 8 + ue] + bias1[0];
      const float gj = sG[ub * 33 + 1 * 8 + ue] + bias1[1];
      const float gf = sG[ub * 33 + 2 * 8 + ue] + bias1[2];
      const float go = sG[ub * 33 + 3 * 8 + ue] + bias1[3];
      const float cn = sig_(gf + 1.0f) * cold + sig_(gi) * tanh_(gj);
      const float hn = sig_(go) * tanh_(cn);
      C1[ub * EDIM + e0 + ue] = cn;
      const u16 hb = f2bf(hn);
      H1buf[wsl * BATCH * EDIM + ub * EDIM + e0 + ue] = hb;
      H1all[((size_t)ub * T_SEQ + t) * EDIM + e0 + ue] = hb;   // GEMM-A layout, row = b*T+t
    }
    grid_barrier(ctr, ++nbar);
  }
}

// ---------------------------------------------------------------- per-row log-softmax NLL
__global__ void softmax_nll_kernel(const float* __restrict__ logits, const int* __restrict__ labels,
                                   float* __restrict__ nll) {
  __shared__ float red[256];
  const int r = blockIdx.x, tid = threadIdx.x;
  const float* row = logits + (size_t)r * VOCAB;
  float m = -1e30f;
  for (int i = tid; i < VOCAB; i += 256) m = fmaxf(m, row[i]);
  red[tid] = m; __syncthreads();
  for (int s = 128; s > 0; s >>= 1) { if (tid < s) red[tid] = fmaxf(red[tid], red[tid + s]); __syncthreads(); }
  m = red[0]; __syncthreads();
  float sum = 0.f;
  for (int i = tid; i < VOCAB; i += 256) sum += __expf(row[i] - m);
  red[tid] = sum; __syncthreads();
  for (int s = 128; s > 0; s >>= 1) { if (tid < s) red[tid] += red[tid + s]; __syncthreads(); }
  if (tid == 0) nll[r] = (m + __logf(red[0])) - row[labels[r]];
}

__global__ void ppl_kernel(const float* __restrict__ nll, float* __restrict__ out) {
  __shared__ float red[256];
  const int tid = threadIdx.x;
  float s = 0.f;
  for (int i = tid; i < ROWS; i += 256) s += nll[i];
  red[tid] = s; __syncthreads();
  for (int st = 128; st > 0; st >>= 1) { if (tid < st) red[tid] += red[tid + st]; __syncthreads(); }
  if (tid == 0) out[(size_t)ROWS * VOCAB] = __expf(red[0] / (float)ROWS);
}

// ---------------------------------------------------------------- host
extern "C" void kernel_launch(void* const* d_in, const int* in_sizes, int n_in,
                              void* d_out, int out_size, void* d_ws, size_t ws_size,
                              hipStream_t stream) {
  const int*   inputs = (const int*)d_in[0];
  const int*   labels = (const int*)d_in[1];
  const float* Emat   = (const float*)d_in[2];
  const float* Wx0    = (const float*)d_in[3];
  const float* Wh0    = (const float*)d_in[4];
  const float* b0     = (const float*)d_in[5];
  const float* Wx1    = (const float*)d_in[6];
  const float* Wh1    = (const float*)d_in[7];
  const float* b1     = (const float*)d_in[8];
  const float* Wd     = (const float*)d_in[9];
  const float* bd     = (const float*)d_in[10];

  char* ws = (char*)d_ws;
  size_t off = 0;
  auto alloc = [&](size_t bytes) { size_t o = off; off += (bytes + 255) & ~(size_t)255; return o; };
  u16* embeds = (u16*)(ws + alloc((size_t)ROWS * EDIM * 2));          // bf16 A for bulk GEMM
  u16* Wx0T   = (u16*)(ws + alloc((size_t)G4 * EDIM * 2));
  u16* Wh0T   = (u16*)(ws + alloc((size_t)G4 * EDIM * 2));
  u16* W1T    = (u16*)(ws + alloc((size_t)G4 * 2 * EDIM * 2));        // [Wx1;Wh1] cols, rows of 1024
  u16* WdT    = (u16*)(ws + alloc((size_t)VOCAB * EDIM * 2));
  u16* Xpre0  = (u16*)(ws + alloc((size_t)ROWS * G4 * 2));
  u16* H1all  = (u16*)(ws + alloc((size_t)ROWS * EDIM * 2));
  char* zbase = ws + off;                                             // ---- zeroed region ----
  u16*   Hbuf0 = (u16*)(ws + alloc(2 * BATCH * EDIM * 2));
  u16*   H1buf = (u16*)(ws + alloc(2 * BATCH * EDIM * 2));
  float* C0    = (float*)(ws + alloc(BATCH * EDIM * 4));
  float* C1    = (float*)(ws + alloc(BATCH * EDIM * 4));
  unsigned* ctr = (unsigned*)(ws + alloc(256));
  float* nll   = (float*)(ws + alloc(ROWS * 4));
  const size_t zbytes = (size_t)((ws + off) - zbase);

  const int n16 = (int)(zbytes / 16);
  zero_kernel<<<(n16 + 255) / 256, 256, 0, stream>>>((uint4*)zbase, n16);
  gather_kernel<<<ROWS, 256, 0, stream>>>(inputs, Emat, embeds);
  transpose_cast_kernel<<<dim3(G4 / 32, EDIM / 32), 256, 0, stream>>>(Wx0, Wx0T, G4, EDIM, 0);
  transpose_cast_kernel<<<dim3(G4 / 32, EDIM / 32), 256, 0, stream>>>(Wh0, Wh0T, G4, EDIM, 0);
  transpose_cast_kernel<<<dim3(G4 / 32, EDIM / 32), 256, 0, stream>>>(Wx1, W1T, G4, 2 * EDIM, 0);
  transpose_cast_kernel<<<dim3(G4 / 32, EDIM / 32), 256, 0, stream>>>(Wh1, W1T, G4, 2 * EDIM, EDIM);
  transpose_cast_kernel<<<dim3(VOCAB / 32, EDIM / 32), 256, 0, stream>>>(Wd, WdT, VOCAB, EDIM, 0);
  // Xpre0 = embeds @ Wx0 (bias added in lstm kernel)
  gemm_bt_kernel<1, 0><<<dim3(G4 / 128, ROWS / 128), 256, 0, stream>>>(embeds, Wx0T, Xpre0, nullptr, ROWS, G4, EDIM);
  lstm_kernel<<<64, 256, 0, stream>>>(Xpre0, Wh0T, W1T, b0, b1, Hbuf0, H1buf, C0, C1, H1all, ctr);
  // logits = H1all @ Wd + bd  -> d_out
  gemm_bt_kernel<0, 1><<<dim3(VOCAB / 128, ROWS / 128), 256, 0, stream>>>(H1all, WdT, d_out, bd, ROWS, VOCAB, EDIM);
  softmax_nll_kernel<<<ROWS, 256, 0, stream>>>((const float*)d_out, labels, nll);
  ppl_kernel<<<1, 256, 0, stream>>>(nll, (float*)d_out);
}